// Round 2
// baseline (1392.820 us; speedup 1.0000x reference)
//
#include <hip/hip_runtime.h>
#include <math.h>

#define BB 4
#define NN 4096
#define KNNK 16
#define DD 128
#define BN (BB*NN)

// ---------------------------------------------------------------------------
// mv16: acc[p] += sum_f A[p][f] * W[f*128 + t], A in LDS ([16][128], 16B aligned),
// W in global (column t). A-tile reads are wave-uniform (broadcast).
// ---------------------------------------------------------------------------
__device__ __forceinline__ void mv16(const float* __restrict__ Wcol,
                                     const float* __restrict__ A,
                                     float acc[16]) {
#pragma unroll 2
  for (int f4 = 0; f4 < 32; ++f4) {
    float w0 = Wcol[(4 * f4 + 0) * 128];
    float w1 = Wcol[(4 * f4 + 1) * 128];
    float w2 = Wcol[(4 * f4 + 2) * 128];
    float w3 = Wcol[(4 * f4 + 3) * 128];
#pragma unroll
    for (int p = 0; p < 16; ++p) {
      float4 a = *reinterpret_cast<const float4*>(A + p * 128 + 4 * f4);
      acc[p] = fmaf(a.w, w3, fmaf(a.z, w2, fmaf(a.y, w1, fmaf(a.x, w0, acc[p]))));
    }
  }
}

// ---------------------------------------------------------------------------
// KNN: 256 blocks, 256 threads. Block = 64 queries of one batch; wave s scans
// candidate split [s*1024, (s+1)*1024); stable 4-way merge by wave 0.
// Distance formula replicates reference exactly (no FMA contraction):
//   d = (sq_n - 2*dot) + sq_m,  sq = (x*x + y*y) + z*z, dot = (x0y0+x1y1)+x2y2
// ---------------------------------------------------------------------------
__global__ __launch_bounds__(256, 2) void knn_kernel(const float* __restrict__ xyz,
                                                     int* __restrict__ knn) {
  const int b = blockIdx.x >> 6;
  const int q0 = (blockIdx.x & 63) * 64;
  const int s = threadIdx.x >> 6;
  const int lane = threadIdx.x & 63;
  const int n = q0 + lane;
  const float* xb = xyz + (size_t)b * NN * 3;

  float qx = xb[n * 3 + 0], qy = xb[n * 3 + 1], qz = xb[n * 3 + 2];
  float qsq = __fadd_rn(__fadd_rn(__fmul_rn(qx, qx), __fmul_rn(qy, qy)),
                        __fmul_rn(qz, qz));

  float dist[16];
  int idx[16];
#pragma unroll
  for (int i = 0; i < 16; ++i) { dist[i] = 3.4e38f; idx[i] = -1; }

  __shared__ float4 cbuf[4][64];
  __shared__ float md[64 * 69];
  __shared__ int mi[64 * 69];

  for (int it = 0; it < 16; ++it) {
    const int cbase = s * 1024 + it * 64;
    const int c = cbase + lane;
    float cx = xb[c * 3 + 0], cy = xb[c * 3 + 1], cz = xb[c * 3 + 2];
    float csq = __fadd_rn(__fadd_rn(__fmul_rn(cx, cx), __fmul_rn(cy, cy)),
                          __fmul_rn(cz, cz));
    __syncthreads();  // previous iteration's readers done
    cbuf[s][lane] = make_float4(cx, cy, cz, csq);
    __syncthreads();
    for (int j = 0; j < 64; ++j) {
      float4 cd = cbuf[s][j];
      float dot = __fadd_rn(__fadd_rn(__fmul_rn(qx, cd.x), __fmul_rn(qy, cd.y)),
                            __fmul_rn(qz, cd.z));
      float d = __fadd_rn(__fsub_rn(qsq, __fmul_rn(2.0f, dot)), cd.w);
      if (d < dist[15]) {
        const int ci = cbase + j;
        int p = 0;
#pragma unroll
        for (int u = 0; u < 16; ++u) p += (dist[u] <= d) ? 1 : 0;
#pragma unroll
        for (int u = 15; u >= 1; --u) {
          bool sh = (u > p);
          dist[u] = sh ? dist[u - 1] : dist[u];
          idx[u] = sh ? idx[u - 1] : idx[u];
        }
#pragma unroll
        for (int u = 0; u < 16; ++u) {
          if (u == p) { dist[u] = d; idx[u] = ci; }
        }
      }
    }
  }
#pragma unroll
  for (int u = 0; u < 16; ++u) {
    md[lane * 69 + s * 17 + u] = dist[u];
    mi[lane * 69 + s * 17 + u] = idx[u];
  }
  __syncthreads();
  if (s == 0) {
    int p0 = 0, p1 = 0, p2 = 0, p3 = 0;
    int* outp = knn + ((size_t)(b * NN + n)) * KNNK;
    const float INF = 3.4e38f;
    for (int k = 0; k < 16; ++k) {
      float d0 = (p0 < 16) ? md[lane * 69 + 0 * 17 + p0] : INF;
      float d1 = (p1 < 16) ? md[lane * 69 + 1 * 17 + p1] : INF;
      float d2 = (p2 < 16) ? md[lane * 69 + 2 * 17 + p2] : INF;
      float d3 = (p3 < 16) ? md[lane * 69 + 3 * 17 + p3] : INF;
      int i0 = (p0 < 16) ? mi[lane * 69 + 0 * 17 + p0] : 0x7fffffff;
      int i1 = (p1 < 16) ? mi[lane * 69 + 1 * 17 + p1] : 0x7fffffff;
      int i2 = (p2 < 16) ? mi[lane * 69 + 2 * 17 + p2] : 0x7fffffff;
      int i3 = (p3 < 16) ? mi[lane * 69 + 3 * 17 + p3] : 0x7fffffff;
      float bd = d0; int bi = i0; int bp = 0;
      if (d1 < bd || (d1 == bd && i1 < bi)) { bd = d1; bi = i1; bp = 1; }
      if (d2 < bd || (d2 == bd && i2 < bi)) { bd = d2; bi = i2; bp = 2; }
      if (d3 < bd || (d3 == bd && i3 < bi)) { bd = d3; bi = i3; bp = 3; }
      outp[k] = bi;
      if (bp == 0) ++p0; else if (bp == 1) ++p1; else if (bp == 2) ++p2; else ++p3;
    }
  }
}

// ---------------------------------------------------------------------------
// Per-point MLP chain: h0=relu(xyz@W0a+b0a); feat=h0@W0b+b0b (=pre);
// x=feat@W1+b1; q=x@Wq; k=x@Wk; v=x@Wv.  16 points/block, thread = out dim.
// ---------------------------------------------------------------------------
__global__ __launch_bounds__(128, 2) void point_mlp_kernel(
    const float* __restrict__ xyz, const float* __restrict__ W0a,
    const float* __restrict__ b0a, const float* __restrict__ W0b,
    const float* __restrict__ b0b, const float* __restrict__ W1,
    const float* __restrict__ b1, const float* __restrict__ Wq,
    const float* __restrict__ Wk, const float* __restrict__ Wv,
    float* __restrict__ pre, float* __restrict__ qv, float* __restrict__ kv,
    float* __restrict__ vv) {
  const int t = threadIdx.x;
  const int g0 = blockIdx.x * 16;
  __shared__ float4 pool[2 * 512 + 16];  // bufA 2048 + bufB 2048 + xs 64 floats
  float* bufA = (float*)pool;
  float* bufB = bufA + 2048;
  float* xs = bufB + 2048;  // [16][4]
  if (t < 48) {
    int p = t / 3, c = t % 3;
    xs[p * 4 + c] = xyz[(size_t)(g0 + p) * 3 + c];
  }
  __syncthreads();
  {
    float wa0 = W0a[t], wa1 = W0a[128 + t], wa2 = W0a[256 + t], ba = b0a[t];
#pragma unroll
    for (int p = 0; p < 16; ++p) {
      float v = fmaf(xs[p * 4 + 2], wa2,
                     fmaf(xs[p * 4 + 1], wa1, fmaf(xs[p * 4 + 0], wa0, ba)));
      bufA[p * 128 + t] = fmaxf(v, 0.f);
    }
  }
  __syncthreads();
  float acc[16];
  {  // feat = h0 @ W0b + b0b  -> bufB, pre
    float bb = b0b[t];
#pragma unroll
    for (int p = 0; p < 16; ++p) acc[p] = bb;
    mv16(W0b + t, bufA, acc);
#pragma unroll
    for (int p = 0; p < 16; ++p) {
      bufB[p * 128 + t] = acc[p];
      pre[(size_t)(g0 + p) * 128 + t] = acc[p];
    }
  }
  __syncthreads();
  {  // x = feat @ W1 + b1 -> bufA
    float bb = b1[t];
#pragma unroll
    for (int p = 0; p < 16; ++p) acc[p] = bb;
    mv16(W1 + t, bufB, acc);
#pragma unroll
    for (int p = 0; p < 16; ++p) bufA[p * 128 + t] = acc[p];
  }
  __syncthreads();
  {
#pragma unroll
    for (int p = 0; p < 16; ++p) acc[p] = 0.f;
    mv16(Wq + t, bufA, acc);
#pragma unroll
    for (int p = 0; p < 16; ++p) qv[(size_t)(g0 + p) * 128 + t] = acc[p];
  }
  {
#pragma unroll
    for (int p = 0; p < 16; ++p) acc[p] = 0.f;
    mv16(Wk + t, bufA, acc);
#pragma unroll
    for (int p = 0; p < 16; ++p) kv[(size_t)(g0 + p) * 128 + t] = acc[p];
  }
  {
#pragma unroll
    for (int p = 0; p < 16; ++p) acc[p] = 0.f;
    mv16(Wv + t, bufA, acc);
#pragma unroll
    for (int p = 0; p < 16; ++p) vv[(size_t)(g0 + p) * 128 + t] = acc[p];
  }
}

// ---------------------------------------------------------------------------
// Attention: one block (128 threads) per (b,n). Thread = feature dim d.
// Softmax over K is thread-local (all 16 logits for dim d live in registers).
// LDS pool: 4 x [16][128] bufs + rbuf[128] = 8320 floats = 2080 float4.
// ---------------------------------------------------------------------------
__global__ __launch_bounds__(128, 2) void attn_kernel(
    const float* __restrict__ xyz, const int* __restrict__ knn,
    const float* __restrict__ pre, const float* __restrict__ qv,
    const float* __restrict__ kv, const float* __restrict__ vv,
    const float* __restrict__ Wd1, const float* __restrict__ bd1,
    const float* __restrict__ Wd2, const float* __restrict__ bd2,
    const float* __restrict__ Wg1, const float* __restrict__ bg1,
    const float* __restrict__ Wg2, const float* __restrict__ bg2,
    const float* __restrict__ W2, const float* __restrict__ b2,
    float* __restrict__ out_res, float* __restrict__ out_attn) {
  const int t = threadIdx.x;
  const int bn = blockIdx.x;
  const int b = bn >> 12;
  __shared__ float4 pool[2080];       // 8320 floats (was 2056: LDS OOB crash)
  float* bufP1 = (float*)pool;        // relu(delta@Wd1+bd1)   [16][128]
  float* bufPE = bufP1 + 2048;        // pos_enc               [16][128]
  float* bufH = bufPE + 2048;         // h = q - kf + pos_enc  [16][128]
  float* bufG = bufH + 2048;          // relu(h@Wg1+bg1)       [16][128]
  float* rbuf = bufG + 2048;          // res pre-W2            [128]
  __shared__ int s_idx[16];
  __shared__ float s_delta[48];

  if (t < 16) s_idx[t] = knn[(size_t)bn * 16 + t];
  __syncthreads();
  if (t < 48) {
    int k = t / 3, c = t % 3;
    s_delta[t] = xyz[(size_t)bn * 3 + c] -
                 xyz[((size_t)(b << 12) + s_idx[k]) * 3 + c];
  }
  __syncthreads();
  {  // pos1 = relu(delta @ Wd1 + bd1)
    float w0 = Wd1[t], w1 = Wd1[128 + t], w2 = Wd1[256 + t], bb = bd1[t];
#pragma unroll
    for (int k = 0; k < 16; ++k) {
      float v = fmaf(s_delta[k * 3 + 2], w2,
                     fmaf(s_delta[k * 3 + 1], w1, fmaf(s_delta[k * 3 + 0], w0, bb)));
      bufP1[k * 128 + t] = fmaxf(v, 0.f);
    }
  }
  __syncthreads();
  float acc[16];
  {  // pos_enc = pos1 @ Wd2 + bd2 ; h = q - kf + pos_enc
    float bb = bd2[t];
#pragma unroll
    for (int k = 0; k < 16; ++k) acc[k] = bb;
    mv16(Wd2 + t, bufP1, acc);
    float qq = qv[(size_t)bn * 128 + t];
#pragma unroll
    for (int k = 0; k < 16; ++k) {
      bufPE[k * 128 + t] = acc[k];
      float kval = kv[((size_t)(b << 12) + s_idx[k]) * 128 + t];
      bufH[k * 128 + t] = qq - kval + acc[k];
    }
  }
  __syncthreads();
  {  // g1 = relu(h @ Wg1 + bg1)
    float bb = bg1[t];
#pragma unroll
    for (int k = 0; k < 16; ++k) acc[k] = bb;
    mv16(Wg1 + t, bufH, acc);
#pragma unroll
    for (int k = 0; k < 16; ++k) bufG[k * 128 + t] = fmaxf(acc[k], 0.f);
  }
  __syncthreads();
  {  // logits = g1 @ Wg2 + bg2
    float bb = bg2[t];
#pragma unroll
    for (int k = 0; k < 16; ++k) acc[k] = bb;
    mv16(Wg2 + t, bufG, acc);
  }
  // softmax over k (axis=-2), scale 1/sqrt(128)
  const float inv = 0.0883883476483184f;
  float m = -3.4e38f;
#pragma unroll
  for (int k = 0; k < 16; ++k) m = fmaxf(m, acc[k] * inv);
  float e[16];
  float ssum = 0.f;
#pragma unroll
  for (int k = 0; k < 16; ++k) {
    e[k] = expf(acc[k] * inv - m);
    ssum += e[k];
  }
  float r = 0.f;
#pragma unroll
  for (int k = 0; k < 16; ++k) {
    float a = e[k] / ssum;
    out_attn[((size_t)bn * 16 + k) * 128 + t] = a;
    float vval = vv[((size_t)(b << 12) + s_idx[k]) * 128 + t];
    r = fmaf(a, vval + bufPE[k * 128 + t], r);
  }
  rbuf[t] = r;
  __syncthreads();
  {  // out = res @ W2 + b2 + pre
    float o = b2[t] + pre[(size_t)bn * 128 + t];
#pragma unroll 4
    for (int f4 = 0; f4 < 32; ++f4) {
      float4 rv = *reinterpret_cast<const float4*>(rbuf + 4 * f4);
      o = fmaf(rv.x, W2[(4 * f4 + 0) * 128 + t], o);
      o = fmaf(rv.y, W2[(4 * f4 + 1) * 128 + t], o);
      o = fmaf(rv.z, W2[(4 * f4 + 2) * 128 + t], o);
      o = fmaf(rv.w, W2[(4 * f4 + 3) * 128 + t], o);
    }
    out_res[(size_t)bn * 128 + t] = o;
  }
}

extern "C" void kernel_launch(void* const* d_in, const int* in_sizes, int n_in,
                              void* d_out, int out_size, void* d_ws,
                              size_t ws_size, hipStream_t stream) {
  const float* xyz = (const float*)d_in[0];
  const float* W0a = (const float*)d_in[1];
  const float* b0a = (const float*)d_in[2];
  const float* W0b = (const float*)d_in[3];
  const float* b0b = (const float*)d_in[4];
  const float* W1 = (const float*)d_in[5];
  const float* b1 = (const float*)d_in[6];
  const float* W2 = (const float*)d_in[7];
  const float* b2 = (const float*)d_in[8];
  const float* Wd1 = (const float*)d_in[9];
  const float* bd1 = (const float*)d_in[10];
  const float* Wd2 = (const float*)d_in[11];
  const float* bd2 = (const float*)d_in[12];
  const float* Wg1 = (const float*)d_in[13];
  const float* bg1 = (const float*)d_in[14];
  const float* Wg2 = (const float*)d_in[15];
  const float* bg2 = (const float*)d_in[16];
  const float* Wq = (const float*)d_in[17];
  const float* Wk = (const float*)d_in[18];
  const float* Wv = (const float*)d_in[19];

  char* ws = (char*)d_ws;
  int* knn = (int*)ws;                                 // 1 MB
  float* pre = (float*)(ws + (1 << 20));               // 8 MB
  float* qv = (float*)(ws + (1 << 20) + (8 << 20));    // 8 MB
  float* kv = (float*)(ws + (1 << 20) + (16 << 20));   // 8 MB
  float* vv = (float*)(ws + (1 << 20) + (24 << 20));   // 8 MB

  float* out_res = (float*)d_out;
  float* out_attn = out_res + (size_t)BN * DD;

  hipLaunchKernelGGL(knn_kernel, dim3(256), dim3(256), 0, stream, xyz, knn);
  hipLaunchKernelGGL(point_mlp_kernel, dim3(1024), dim3(128), 0, stream, xyz,
                     W0a, b0a, W0b, b0b, W1, b1, Wq, Wk, Wv, pre, qv, kv, vv);
  hipLaunchKernelGGL(attn_kernel, dim3(16384), dim3(128), 0, stream, xyz, knn,
                     pre, qv, kv, vv, Wd1, bd1, Wd2, bd2, Wg1, bg1, Wg2, bg2,
                     W2, b2, out_res, out_attn);
}

// Round 3
// 908.961 us; speedup vs baseline: 1.5323x; 1.5323x over previous
//
#include <hip/hip_runtime.h>
#include <math.h>

#define BB 4
#define NN 4096
#define KNNK 16
#define DD 128
#define BN (BB*NN)

typedef __attribute__((ext_vector_type(8))) short short8;   // 8 bf16
typedef __attribute__((ext_vector_type(4))) float floatx4;  // MFMA acc

__device__ __forceinline__ short f2bf(float x) {
  unsigned u = __float_as_uint(x);
  unsigned r = (u + 0x7fffu + ((u >> 16) & 1u)) >> 16;
  return (short)r;
}

// ---------------------------------------------------------------------------
// mv16: acc[p] += sum_f A[p][f] * W[f*128 + t]  (A in LDS, wave-broadcast reads)
// ---------------------------------------------------------------------------
__device__ __forceinline__ void mv16(const float* __restrict__ Wcol,
                                     const float* __restrict__ A,
                                     float acc[16]) {
#pragma unroll 2
  for (int f4 = 0; f4 < 32; ++f4) {
    float w0 = Wcol[(4 * f4 + 0) * 128];
    float w1 = Wcol[(4 * f4 + 1) * 128];
    float w2 = Wcol[(4 * f4 + 2) * 128];
    float w3 = Wcol[(4 * f4 + 3) * 128];
#pragma unroll
    for (int p = 0; p < 16; ++p) {
      float4 a = *reinterpret_cast<const float4*>(A + p * 128 + 4 * f4);
      acc[p] = fmaf(a.w, w3, fmaf(a.z, w2, fmaf(a.y, w1, fmaf(a.x, w0, acc[p]))));
    }
  }
}

// ---------------------------------------------------------------------------
// KNN (unchanged from verified baseline)
// ---------------------------------------------------------------------------
__global__ __launch_bounds__(256, 2) void knn_kernel(const float* __restrict__ xyz,
                                                     int* __restrict__ knn) {
  const int b = blockIdx.x >> 6;
  const int q0 = (blockIdx.x & 63) * 64;
  const int s = threadIdx.x >> 6;
  const int lane = threadIdx.x & 63;
  const int n = q0 + lane;
  const float* xb = xyz + (size_t)b * NN * 3;

  float qx = xb[n * 3 + 0], qy = xb[n * 3 + 1], qz = xb[n * 3 + 2];
  float qsq = __fadd_rn(__fadd_rn(__fmul_rn(qx, qx), __fmul_rn(qy, qy)),
                        __fmul_rn(qz, qz));

  float dist[16];
  int idx[16];
#pragma unroll
  for (int i = 0; i < 16; ++i) { dist[i] = 3.4e38f; idx[i] = -1; }

  __shared__ float4 cbuf[4][64];
  __shared__ float md[64 * 69];
  __shared__ int mi[64 * 69];

  for (int it = 0; it < 16; ++it) {
    const int cbase = s * 1024 + it * 64;
    const int c = cbase + lane;
    float cx = xb[c * 3 + 0], cy = xb[c * 3 + 1], cz = xb[c * 3 + 2];
    float csq = __fadd_rn(__fadd_rn(__fmul_rn(cx, cx), __fmul_rn(cy, cy)),
                          __fmul_rn(cz, cz));
    __syncthreads();
    cbuf[s][lane] = make_float4(cx, cy, cz, csq);
    __syncthreads();
    for (int j = 0; j < 64; ++j) {
      float4 cd = cbuf[s][j];
      float dot = __fadd_rn(__fadd_rn(__fmul_rn(qx, cd.x), __fmul_rn(qy, cd.y)),
                            __fmul_rn(qz, cd.z));
      float d = __fadd_rn(__fsub_rn(qsq, __fmul_rn(2.0f, dot)), cd.w);
      if (d < dist[15]) {
        const int ci = cbase + j;
        int p = 0;
#pragma unroll
        for (int u = 0; u < 16; ++u) p += (dist[u] <= d) ? 1 : 0;
#pragma unroll
        for (int u = 15; u >= 1; --u) {
          bool sh = (u > p);
          dist[u] = sh ? dist[u - 1] : dist[u];
          idx[u] = sh ? idx[u - 1] : idx[u];
        }
#pragma unroll
        for (int u = 0; u < 16; ++u) {
          if (u == p) { dist[u] = d; idx[u] = ci; }
        }
      }
    }
  }
#pragma unroll
  for (int u = 0; u < 16; ++u) {
    md[lane * 69 + s * 17 + u] = dist[u];
    mi[lane * 69 + s * 17 + u] = idx[u];
  }
  __syncthreads();
  if (s == 0) {
    int p0 = 0, p1 = 0, p2 = 0, p3 = 0;
    int* outp = knn + ((size_t)(b * NN + n)) * KNNK;
    const float INF = 3.4e38f;
    for (int k = 0; k < 16; ++k) {
      float d0 = (p0 < 16) ? md[lane * 69 + 0 * 17 + p0] : INF;
      float d1 = (p1 < 16) ? md[lane * 69 + 1 * 17 + p1] : INF;
      float d2 = (p2 < 16) ? md[lane * 69 + 2 * 17 + p2] : INF;
      float d3 = (p3 < 16) ? md[lane * 69 + 3 * 17 + p3] : INF;
      int i0 = (p0 < 16) ? mi[lane * 69 + 0 * 17 + p0] : 0x7fffffff;
      int i1 = (p1 < 16) ? mi[lane * 69 + 1 * 17 + p1] : 0x7fffffff;
      int i2 = (p2 < 16) ? mi[lane * 69 + 2 * 17 + p2] : 0x7fffffff;
      int i3 = (p3 < 16) ? mi[lane * 69 + 3 * 17 + p3] : 0x7fffffff;
      float bd = d0; int bi = i0; int bp = 0;
      if (d1 < bd || (d1 == bd && i1 < bi)) { bd = d1; bi = i1; bp = 1; }
      if (d2 < bd || (d2 == bd && i2 < bi)) { bd = d2; bi = i2; bp = 2; }
      if (d3 < bd || (d3 == bd && i3 < bi)) { bd = d3; bi = i3; bp = 3; }
      outp[k] = bi;
      if (bp == 0) ++p0; else if (bp == 1) ++p1; else if (bp == 2) ++p2; else ++p3;
    }
  }
}

// ---------------------------------------------------------------------------
// Per-point MLP chain (unchanged from verified baseline)
// ---------------------------------------------------------------------------
__global__ __launch_bounds__(128, 2) void point_mlp_kernel(
    const float* __restrict__ xyz, const float* __restrict__ W0a,
    const float* __restrict__ b0a, const float* __restrict__ W0b,
    const float* __restrict__ b0b, const float* __restrict__ W1,
    const float* __restrict__ b1, const float* __restrict__ Wq,
    const float* __restrict__ Wk, const float* __restrict__ Wv,
    float* __restrict__ pre, float* __restrict__ qv, float* __restrict__ kv,
    float* __restrict__ vv) {
  const int t = threadIdx.x;
  const int g0 = blockIdx.x * 16;
  __shared__ float4 pool[2 * 512 + 16];
  float* bufA = (float*)pool;
  float* bufB = bufA + 2048;
  float* xs = bufB + 2048;  // [16][4]
  if (t < 48) {
    int p = t / 3, c = t % 3;
    xs[p * 4 + c] = xyz[(size_t)(g0 + p) * 3 + c];
  }
  __syncthreads();
  {
    float wa0 = W0a[t], wa1 = W0a[128 + t], wa2 = W0a[256 + t], ba = b0a[t];
#pragma unroll
    for (int p = 0; p < 16; ++p) {
      float v = fmaf(xs[p * 4 + 2], wa2,
                     fmaf(xs[p * 4 + 1], wa1, fmaf(xs[p * 4 + 0], wa0, ba)));
      bufA[p * 128 + t] = fmaxf(v, 0.f);
    }
  }
  __syncthreads();
  float acc[16];
  {
    float bb = b0b[t];
#pragma unroll
    for (int p = 0; p < 16; ++p) acc[p] = bb;
    mv16(W0b + t, bufA, acc);
#pragma unroll
    for (int p = 0; p < 16; ++p) {
      bufB[p * 128 + t] = acc[p];
      pre[(size_t)(g0 + p) * 128 + t] = acc[p];
    }
  }
  __syncthreads();
  {
    float bb = b1[t];
#pragma unroll
    for (int p = 0; p < 16; ++p) acc[p] = bb;
    mv16(W1 + t, bufB, acc);
#pragma unroll
    for (int p = 0; p < 16; ++p) bufA[p * 128 + t] = acc[p];
  }
  __syncthreads();
  {
#pragma unroll
    for (int p = 0; p < 16; ++p) acc[p] = 0.f;
    mv16(Wq + t, bufA, acc);
#pragma unroll
    for (int p = 0; p < 16; ++p) qv[(size_t)(g0 + p) * 128 + t] = acc[p];
  }
  {
#pragma unroll
    for (int p = 0; p < 16; ++p) acc[p] = 0.f;
    mv16(Wk + t, bufA, acc);
#pragma unroll
    for (int p = 0; p < 16; ++p) kv[(size_t)(g0 + p) * 128 + t] = acc[p];
  }
  {
#pragma unroll
    for (int p = 0; p < 16; ++p) acc[p] = 0.f;
    mv16(Wv + t, bufA, acc);
#pragma unroll
    for (int p = 0; p < 16; ++p) vv[(size_t)(g0 + p) * 128 + t] = acc[p];
  }
}

// ---------------------------------------------------------------------------
// Weight pre-swizzle: Wd2/Wg1/Wg2 (fp32 [k(128)][n(128)]) -> bf16 B-fragment
// order for mfma_f32_16x16x32_bf16: wsw[stage][nt][ks][lane][j],
// element = W[(ks*32 + (lane>>4)*8 + j)*128 + nt*16 + (lane&15)].
// ---------------------------------------------------------------------------
__global__ void swz_kernel(const float* __restrict__ Wd2,
                           const float* __restrict__ Wg1,
                           const float* __restrict__ Wg2,
                           short* __restrict__ wsw) {
  int t = blockIdx.x * 256 + threadIdx.x;  // [0, 6144): [stage][nt][ks][lane]
  if (t >= 3 * 2048) return;
  int stage = t / 2048;
  int rem = t % 2048;
  int nt = rem / 256;
  int ks = (rem % 256) / 64;
  int lane = rem % 64;
  const float* W = (stage == 0) ? Wd2 : (stage == 1) ? Wg1 : Wg2;
  short8 o;
#pragma unroll
  for (int j = 0; j < 8; ++j) {
    int k = ks * 32 + (lane >> 4) * 8 + j;
    int n = nt * 16 + (lane & 15);
    o[j] = f2bf(W[k * 128 + n]);
  }
  *reinterpret_cast<short8*>(wsw + (size_t)t * 8) = o;
}

// ---------------------------------------------------------------------------
// MFMA attention: 4 waves/block, one point per wave. M=16 neighbors,
// N=128 (8 tiles), K=128 (4 steps) per stage; 3 MFMA stages (Wd2,Wg1,Wg2).
// Verified 16x16x32 layouts: A: m=lane&15, k=(lane>>4)*8+j; B: n=lane&15,
// same k; C/D: col=lane&15, row=(lane>>4)*4+reg.
// ---------------------------------------------------------------------------
__global__ __launch_bounds__(256, 2) void attn_mfma_kernel(
    const float* __restrict__ xyz, const int* __restrict__ knn,
    const float* __restrict__ qv, const float* __restrict__ kv,
    const float* __restrict__ vv, const short* __restrict__ wsw,
    const float* __restrict__ Wd1, const float* __restrict__ bd1,
    const float* __restrict__ bd2, const float* __restrict__ bg1,
    const float* __restrict__ bg2, float* __restrict__ res_ws,
    float* __restrict__ out_attn) {
  const int wv = threadIdx.x >> 6;
  const int lane = threadIdx.x & 63;
  const int g = lane >> 4;   // lane group 0..3
  const int c = lane & 15;   // column-in-tile / A-row
  const int bn = blockIdx.x * 4 + wv;
  const int b = bn >> 12;

  // per-wave LDS: conv = 16 rows x 136 bf16 (stride 272B, 16B-aligned rows)
  __shared__ __attribute__((aligned(16))) short conv[4][16 * 136];
  __shared__ int sidx[4][16];
  __shared__ float sdelta[4][64];  // [16][4] padded

  if (lane < 16) sidx[wv][lane] = knn[(size_t)bn * 16 + lane];
  __syncthreads();
  if (lane < 48) {
    int k = lane / 3, cc = lane % 3;
    sdelta[wv][k * 4 + cc] = xyz[(size_t)bn * 3 + cc] -
                             xyz[((size_t)(b << 12) + sidx[wv][k]) * 3 + cc];
  }
  __syncthreads();

  // ---- P1 = relu(delta @ Wd1 + bd1) directly as A-fragments ----
  short8 af[4];
  {
    float ddx = sdelta[wv][c * 4 + 0];
    float ddy = sdelta[wv][c * 4 + 1];
    float ddz = sdelta[wv][c * 4 + 2];
#pragma unroll
    for (int s = 0; s < 4; ++s) {
#pragma unroll
      for (int j = 0; j < 8; ++j) {
        int d = s * 32 + g * 8 + j;
        float v = fmaf(ddz, Wd1[256 + d],
                       fmaf(ddy, Wd1[128 + d], fmaf(ddx, Wd1[d], bd1[d])));
        af[s][j] = f2bf(fmaxf(v, 0.f));
      }
    }
  }

  // per-nt scalars
  float qc[8], bd2v[8], bg1v[8], bg2v[8];
#pragma unroll
  for (int nt = 0; nt < 8; ++nt) {
    qc[nt] = qv[(size_t)bn * 128 + nt * 16 + c];
    bd2v[nt] = bd2[nt * 16 + c];
    bg1v[nt] = bg1[nt * 16 + c];
    bg2v[nt] = bg2[nt * 16 + c];
  }

  floatx4 acc[8];

  // ---- stage 1: PE = P1 @ Wd2 + bd2 ----
#pragma unroll
  for (int nt = 0; nt < 8; ++nt) acc[nt] = (floatx4){0.f, 0.f, 0.f, 0.f};
  {
    const short* Wst = wsw;  // stage 0
#pragma unroll
    for (int ks = 0; ks < 4; ++ks) {
#pragma unroll
      for (int nt = 0; nt < 8; ++nt) {
        short8 bf = *reinterpret_cast<const short8*>(
            Wst + ((size_t)(nt * 4 + ks) * 64 + lane) * 8);
        acc[nt] = __builtin_amdgcn_mfma_f32_16x16x32_bf16(af[ks], bf, acc[nt],
                                                          0, 0, 0);
      }
    }
  }

  // ---- H = q - kf + PE ; PE kept fp32 ; H -> LDS (bf16, C-layout) ----
  float PE[8][4];
  int idxr[4];
#pragma unroll
  for (int r = 0; r < 4; ++r) idxr[r] = sidx[wv][g * 4 + r];
#pragma unroll
  for (int nt = 0; nt < 8; ++nt) {
#pragma unroll
    for (int r = 0; r < 4; ++r) {
      float pe = acc[nt][r] + bd2v[nt];
      PE[nt][r] = pe;
      float kvv = kv[((size_t)(b << 12) + idxr[r]) * 128 + nt * 16 + c];
      conv[wv][(g * 4 + r) * 136 + nt * 16 + c] = f2bf(qc[nt] - kvv + pe);
    }
  }
  __syncthreads();
#pragma unroll
  for (int s = 0; s < 4; ++s)
    af[s] = *reinterpret_cast<const short8*>(&conv[wv][c * 136 + s * 32 + g * 8]);
  __syncthreads();

  // ---- stage 2: G = relu(H @ Wg1 + bg1) ----
#pragma unroll
  for (int nt = 0; nt < 8; ++nt) acc[nt] = (floatx4){0.f, 0.f, 0.f, 0.f};
  {
    const short* Wst = wsw + 16384;  // stage 1
#pragma unroll
    for (int ks = 0; ks < 4; ++ks) {
#pragma unroll
      for (int nt = 0; nt < 8; ++nt) {
        short8 bf = *reinterpret_cast<const short8*>(
            Wst + ((size_t)(nt * 4 + ks) * 64 + lane) * 8);
        acc[nt] = __builtin_amdgcn_mfma_f32_16x16x32_bf16(af[ks], bf, acc[nt],
                                                          0, 0, 0);
      }
    }
  }
#pragma unroll
  for (int nt = 0; nt < 8; ++nt) {
#pragma unroll
    for (int r = 0; r < 4; ++r) {
      conv[wv][(g * 4 + r) * 136 + nt * 16 + c] =
          f2bf(fmaxf(acc[nt][r] + bg1v[nt], 0.f));
    }
  }
  __syncthreads();
#pragma unroll
  for (int s = 0; s < 4; ++s)
    af[s] = *reinterpret_cast<const short8*>(&conv[wv][c * 136 + s * 32 + g * 8]);
  __syncthreads();

  // ---- stage 3: logits = G @ Wg2 + bg2 ----
#pragma unroll
  for (int nt = 0; nt < 8; ++nt) acc[nt] = (floatx4){0.f, 0.f, 0.f, 0.f};
  {
    const short* Wst = wsw + 32768;  // stage 2
#pragma unroll
    for (int ks = 0; ks < 4; ++ks) {
#pragma unroll
      for (int nt = 0; nt < 8; ++nt) {
        short8 bf = *reinterpret_cast<const short8*>(
            Wst + ((size_t)(nt * 4 + ks) * 64 + lane) * 8);
        acc[nt] = __builtin_amdgcn_mfma_f32_16x16x32_bf16(af[ks], bf, acc[nt],
                                                          0, 0, 0);
      }
    }
  }

  // ---- softmax over neighbors (rows): 4 local regs + shfl_xor(16,32) ----
  const float inv = 0.0883883476483184f;  // 1/sqrt(128)
  float resv[8];
#pragma unroll
  for (int nt = 0; nt < 8; ++nt) {
    float l0 = (acc[nt][0] + bg2v[nt]) * inv;
    float l1 = (acc[nt][1] + bg2v[nt]) * inv;
    float l2 = (acc[nt][2] + bg2v[nt]) * inv;
    float l3 = (acc[nt][3] + bg2v[nt]) * inv;
    float m4 = fmaxf(fmaxf(l0, l1), fmaxf(l2, l3));
    m4 = fmaxf(m4, __shfl_xor(m4, 16));
    m4 = fmaxf(m4, __shfl_xor(m4, 32));
    float e0 = expf(l0 - m4), e1 = expf(l1 - m4);
    float e2 = expf(l2 - m4), e3 = expf(l3 - m4);
    float s4 = e0 + e1 + e2 + e3;
    s4 += __shfl_xor(s4, 16);
    s4 += __shfl_xor(s4, 32);
    float rs = 1.f / s4;
    float a0 = e0 * rs, a1 = e1 * rs, a2 = e2 * rs, a3 = e3 * rs;
    size_t base = ((size_t)bn * 16 + g * 4) * 128 + nt * 16 + c;
    out_attn[base + 0 * 128] = a0;
    out_attn[base + 1 * 128] = a1;
    out_attn[base + 2 * 128] = a2;
    out_attn[base + 3 * 128] = a3;
    float r = 0.f;
    {
      float v0 = vv[((size_t)(b << 12) + idxr[0]) * 128 + nt * 16 + c];
      float v1 = vv[((size_t)(b << 12) + idxr[1]) * 128 + nt * 16 + c];
      float v2 = vv[((size_t)(b << 12) + idxr[2]) * 128 + nt * 16 + c];
      float v3 = vv[((size_t)(b << 12) + idxr[3]) * 128 + nt * 16 + c];
      r = fmaf(a0, v0 + PE[nt][0], r);
      r = fmaf(a1, v1 + PE[nt][1], r);
      r = fmaf(a2, v2 + PE[nt][2], r);
      r = fmaf(a3, v3 + PE[nt][3], r);
    }
    r += __shfl_xor(r, 16);
    r += __shfl_xor(r, 32);
    resv[nt] = r;
  }
  if (g == 0) {
#pragma unroll
    for (int nt = 0; nt < 8; ++nt)
      res_ws[(size_t)bn * 128 + nt * 16 + c] = resv[nt];
  }
}

// ---------------------------------------------------------------------------
// Epilogue: out_res = res @ W2 + b2 + pre   (16 points/block, mv16)
// ---------------------------------------------------------------------------
__global__ __launch_bounds__(128, 2) void epilogue_kernel(
    const float* __restrict__ res_ws, const float* __restrict__ W2,
    const float* __restrict__ b2, const float* __restrict__ pre,
    float* __restrict__ out_res) {
  const int t = threadIdx.x;
  const int g0 = blockIdx.x * 16;
  __shared__ __attribute__((aligned(16))) float buf[16 * 128];
#pragma unroll
  for (int p = 0; p < 16; ++p)
    buf[p * 128 + t] = res_ws[(size_t)(g0 + p) * 128 + t];
  __syncthreads();
  float acc[16];
  float bb = b2[t];
#pragma unroll
  for (int p = 0; p < 16; ++p)
    acc[p] = bb + pre[(size_t)(g0 + p) * 128 + t];
  mv16(W2 + t, buf, acc);
#pragma unroll
  for (int p = 0; p < 16; ++p)
    out_res[(size_t)(g0 + p) * 128 + t] = acc[p];
}

extern "C" void kernel_launch(void* const* d_in, const int* in_sizes, int n_in,
                              void* d_out, int out_size, void* d_ws,
                              size_t ws_size, hipStream_t stream) {
  const float* xyz = (const float*)d_in[0];
  const float* W0a = (const float*)d_in[1];
  const float* b0a = (const float*)d_in[2];
  const float* W0b = (const float*)d_in[3];
  const float* b0b = (const float*)d_in[4];
  const float* W1 = (const float*)d_in[5];
  const float* b1 = (const float*)d_in[6];
  const float* W2 = (const float*)d_in[7];
  const float* b2 = (const float*)d_in[8];
  const float* Wd1 = (const float*)d_in[9];
  const float* bd1 = (const float*)d_in[10];
  const float* Wd2 = (const float*)d_in[11];
  const float* bd2 = (const float*)d_in[12];
  const float* Wg1 = (const float*)d_in[13];
  const float* bg1 = (const float*)d_in[14];
  const float* Wg2 = (const float*)d_in[15];
  const float* bg2 = (const float*)d_in[16];
  const float* Wq = (const float*)d_in[17];
  const float* Wk = (const float*)d_in[18];
  const float* Wv = (const float*)d_in[19];

  char* ws = (char*)d_ws;
  int* knn = (int*)ws;                                  // 1 MB
  float* pre = (float*)(ws + (1 << 20));                // 8 MB
  float* qv = (float*)(ws + (9 << 20));                 // 8 MB
  float* kv = (float*)(ws + (17 << 20));                // 8 MB
  float* vv = (float*)(ws + (25 << 20));                // 8 MB
  float* res_ws = (float*)(ws + (33 << 20));            // 8 MB
  short* wsw = (short*)(ws + (41 << 20));               // 96 KB bf16 B-frags

  float* out_res = (float*)d_out;
  float* out_attn = out_res + (size_t)BN * DD;

  hipLaunchKernelGGL(swz_kernel, dim3(24), dim3(256), 0, stream, Wd2, Wg1, Wg2,
                     wsw);
  hipLaunchKernelGGL(knn_kernel, dim3(256), dim3(256), 0, stream, xyz, knn);
  hipLaunchKernelGGL(point_mlp_kernel, dim3(1024), dim3(128), 0, stream, xyz,
                     W0a, b0a, W0b, b0b, W1, b1, Wq, Wk, Wv, pre, qv, kv, vv);
  hipLaunchKernelGGL(attn_mfma_kernel, dim3(4096), dim3(256), 0, stream, xyz,
                     knn, qv, kv, vv, wsw, Wd1, bd1, bd2, bg1, bg2, res_ws,
                     out_attn);
  hipLaunchKernelGGL(epilogue_kernel, dim3(1024), dim3(128), 0, stream, res_ws,
                     W2, b2, pre, out_res);
}